// Round 5
// baseline (401.471 us; speedup 1.0000x reference)
//
#include <hip/hip_runtime.h>
#include <math.h>

#define BB 16
#define CC 1024
#define SS 4096
#define WCH 4                    // s positions per wave-chunk
#define NCH 4                    // chunks per wave
#define WPB 4                    // waves per block (256 threads)
#define KBLK (SS / (WCH * NCH))  // 256 Nk rows per batch

__device__ __forceinline__ float4 shfl_xor_f4(float4 v, int d) {
    v.x = __shfl_xor(v.x, d);
    v.y = __shfl_xor(v.y, d);
    v.z = __shfl_xor(v.z, d);
    v.w = __shfl_xor(v.w, d);
    return v;
}
__device__ __forceinline__ void add4(float4& a, const float4 b) {
    a.x += b.x; a.y += b.y; a.z += b.z; a.w += b.w;
}

// v6: wave-independent chunks. v4/v5 both plateaued at ~115us (2.3 TB/s):
// the block-wide barrier around the cross-wave logit reduce locksteps all
// waves (burst->drain->stall together). Here the reduce NEVER leaves the
// wave: each wave owns 4 s x all 1024 channels (lane l holds channels
// l+64i, i=0..15 -> 16 float4 = 16KB/wave), 6-level shfl_xor butterfly,
// no __syncthreads anywhere. Waves drift freely so serial tails overlap
// other waves' loads. Raw s_barrier (no waitcnt, no data dep) keeps the
// 4 waves of a block aligned so their adjacent 16B quads merge into 64B
// lines. (256,3): 12 waves/CU, 170-VGPR cap -> ~135 live regs, no spill.
__global__ __launch_bounds__(256, 3) void k_fused(
    const float* __restrict__ x, const float* __restrict__ w,
    const float* __restrict__ bias,
    float* __restrict__ Nk, float* __restrict__ sk)
{
    const int bx   = blockIdx.x;   // 0..63: 64-s window per block
    const int b    = blockIdx.y;   // 0..15
    const int t    = threadIdx.x;  // 0..255
    const int wv   = t >> 6;       // 0..3
    const int lane = t & 63;
    const int wid  = bx * WPB + wv;  // 0..255: Nk row within batch

    // per-lane base: batch b, row `lane`, s = bx*64 + wv*4
    const float* xr = x + (size_t)b * CC * SS + (size_t)lane * SS
                        + bx * (WPB * NCH * WCH) + wv * WCH;

    float wreg[16];
#pragma unroll
    for (int i = 0; i < 16; ++i) wreg[i] = w[lane + 64 * i];
    const float bv = bias[0];

    float np[16];
#pragma unroll
    for (int i = 0; i < 16; ++i) np[i] = 0.f;
    float s_part = 0.f;

#pragma unroll
    for (int ch = 0; ch < NCH; ++ch) {
        // ---- 16 loads: rows lane+64i, this wave's s-quad, chunk ch ----
        float4 xv[16];
#pragma unroll
        for (int i = 0; i < 16; ++i)
            xv[i] = *(const float4*)(xr + (size_t)i * 64 * SS
                                        + ch * (WPB * WCH));

        // ---- partial logits over this lane's 16 channels ----
        float4 lacc = make_float4(0.f, 0.f, 0.f, 0.f);
#pragma unroll
        for (int i = 0; i < 16; ++i) {
            lacc.x += xv[i].x * wreg[i];
            lacc.y += xv[i].y * wreg[i];
            lacc.z += xv[i].z * wreg[i];
            lacc.w += xv[i].w * wreg[i];
        }

        // ---- wave-local butterfly: full channel sum, all lanes get it ----
        add4(lacc, shfl_xor_f4(lacc, 1));
        add4(lacc, shfl_xor_f4(lacc, 2));
        add4(lacc, shfl_xor_f4(lacc, 4));
        add4(lacc, shfl_xor_f4(lacc, 8));
        add4(lacc, shfl_xor_f4(lacc, 16));
        add4(lacc, shfl_xor_f4(lacc, 32));

        // ---- softmax weights (no-max: |logit| <~ 1, exp direct) ----
        float4 e;
        e.x = __expf((lacc.x + bv) * 0.03125f);
        e.y = __expf((lacc.y + bv) * 0.03125f);
        e.z = __expf((lacc.z + bv) * 0.03125f);
        e.w = __expf((lacc.w + bv) * 0.03125f);
        s_part += (e.x + e.y) + (e.z + e.w);

        // ---- fold: per-channel weighted sums stay in-lane ----
#pragma unroll
        for (int i = 0; i < 16; ++i)
            np[i] += xv[i].x * e.x + xv[i].y * e.y
                   + xv[i].z * e.z + xv[i].w * e.w;

        // keep the block's 4 waves aligned for 64B line sharing.
        // raw barrier: no data crosses it, so no waitcnt needed.
        __builtin_amdgcn_s_barrier();
    }

    // ---- epilogue: lane owns its channels -> coalesced dword stores ----
    float* NkRow = Nk + (size_t)(b * KBLK + wid) * CC;
#pragma unroll
    for (int i = 0; i < 16; ++i)
        NkRow[lane + 64 * i] = np[i];
    if (lane == 0) sk[b * KBLK + wid] = s_part;
}

// Combine: out[b,c] = (sum_k Nk[k,c]) / (sum_k sk[k]).
// 256 threads: 4 k-groups x 64 channels, LDS combine of the 4 partials.
__global__ __launch_bounds__(256) void k_combine(
    const float* __restrict__ Nk, const float* __restrict__ sk,
    float* __restrict__ out)
{
    __shared__ float part[4][64];

    const int b  = blockIdx.y;
    const int c0 = blockIdx.x * 64;
    const int t  = threadIdx.x;    // 0..255
    const int c  = t & 63;
    const int kg = t >> 6;         // 0..3

    float sv = 0.f;
#pragma unroll
    for (int j = 0; j < 4; ++j) sv += sk[b * KBLK + (t & 63) + 64 * j];
    for (int d = 32; d; d >>= 1) sv += __shfl_xor(sv, d);
    const float D = sv;

    float acc = 0.f;
    const float* Nb = Nk + (size_t)b * KBLK * CC + (size_t)(kg * 64) * CC + c0 + c;
#pragma unroll 8
    for (int j = 0; j < 64; ++j)
        acc += Nb[(size_t)j * CC];
    part[kg][c] = acc;
    __syncthreads();

    if (t < 64)
        out[b * CC + c0 + t] =
            (part[0][t] + part[1][t] + part[2][t] + part[3][t]) / D;
}

extern "C" void kernel_launch(void* const* d_in, const int* in_sizes, int n_in,
                              void* d_out, int out_size, void* d_ws, size_t ws_size,
                              hipStream_t stream) {
    const float* x    = (const float*)d_in[0];  // [16,1024,64,64]
    const float* w    = (const float*)d_in[1];  // [1024]
    const float* bias = (const float*)d_in[2];  // [1]
    float* out = (float*)d_out;                 // [16,1024,1,1]

    float* Nk = (float*)d_ws;                           // 16*256*1024 f32 = 16 MB
    float* sk = Nk + (size_t)BB * KBLK * CC;            // 16*256 f32

    k_fused<<<dim3(SS / (WPB * NCH * WCH), BB), 256, 0, stream>>>(
        x, w, bias, Nk, sk);
    k_combine<<<dim3(CC / 64, BB), 256, 0, stream>>>(Nk, sk, out);
}